// Round 6
// baseline (99671.637 us; speedup 1.0000x reference)
//
#include <hip/hip_runtime.h>
#include <hip/hip_bf16.h>
#include <cmath>

#define FD 32
#define SD 16
#define NSTEP 4096
#define VOCAB 50257
#define CD 48            // FD + SD (logical)
#define SROW 64          // states row stride (padded; rows 256B-aligned)
#define VC 32            // vocab chunks for fused logits consumers
#define ROWS_PER ((VOCAB + VC - 1) / VC)   // 1571
#define NBAND 16         // time bands of 256 steps
#define XSLACK 2         // xt slack rows for prefetch
#define MAGIC 0x5A000000

typedef float v2f __attribute__((ext_vector_type(2)));
typedef float v4f __attribute__((ext_vector_type(4)));

// ---------------- workspace layout (floats) ----------------
#define WS_XT     0
#define WS_STATES ((NSTEP + XSLACK) * 96)
#define WS_PM     (WS_STATES + NSTEP * SROW)
#define WS_NLL    (WS_PM + NSTEP * VC)
#define WS_PROG   (WS_NLL + NSTEP + 64)          // own cache line

__device__ __forceinline__ float rl(float v, int l) {
    return __builtin_bit_cast(float, __builtin_amdgcn_readlane(__builtin_bit_cast(int, v), l));
}

// ---------------- K1: precompute token-dependent terms ----------------
__global__ __launch_bounds__(256) void xterm_kernel(
    const int* __restrict__ tok, const float* __restrict__ embed,
    const float* __restrict__ Wgx, const float* __restrict__ Wxp,
    const float* __restrict__ Wxf, float* __restrict__ xt)
{
    int t = blockIdx.x * 8 + (threadIdx.x >> 5);
    int i = threadIdx.x & 31;
    if (t >= NSTEP) return;
    const float* x = embed + (size_t)tok[t] * FD;
    float a0 = 0.f, a1 = 0.f, a2 = 0.f;
#pragma unroll
    for (int j = 0; j < FD; ++j) {
        float xj = x[j];
        a0 += Wgx[i * FD + j] * xj;
        a1 += Wxp[i * FD + j] * xj;
        a2 += Wxf[i * FD + j] * xj;
    }
    xt[t * 96 + i]      = a0;
    xt[t * 96 + 32 + i] = a1;
    xt[t * 96 + 64 + i] = a2;
}

// ---------------- K2: fused scan (block 0) + logits consumers (blocks 1..512) ----
// Scan = R3 readlane form (measured best). Publishes progress (release, agent
// scope, magic-tagged so 0xAA ws-poison can never satisfy a waiter) every 128
// steps. Consumers: chunk = (b-1)&31 (1571 vocab rows), band = (b-1)>>5 (256
// timesteps), one t per thread; spin-sleep until scan passes band end.
// __launch_bounds__(256,4) -> <=128 VGPR -> >=4 blocks/CU -> 1024-block
// capacity >= 513: all blocks co-resident, no deadlock.
__global__ __launch_bounds__(256, 4) void fused_kernel(
    const float* __restrict__ Wgh, const float* __restrict__ bgh,
    const float* __restrict__ Wff, const float* __restrict__ bff,
    const float* __restrict__ Wfs,
    const float* __restrict__ Wsgf, const float* __restrict__ bsgf,
    const float* __restrict__ Wsgs, const float* __restrict__ Wss,
    const float* __restrict__ bss, const float* __restrict__ Wsf,
    const float* __restrict__ xt, float* __restrict__ states,
    const float* __restrict__ Wout, const float* __restrict__ bout,
    float* __restrict__ pm, int* __restrict__ prog)
{
    if (blockIdx.x == 0) {
        // ================= producer: serial scan =================
        const int lane = threadIdx.x;
        if (lane >= 64) return;

        float wA[FD], wB[FD], wC[SD];
        float bA = 0.f, bB = 0.f;

        if (lane < FD) {
#pragma unroll
            for (int j = 0; j < FD; ++j) { wA[j] = Wgh[lane * FD + j]; wB[j] = Wff[lane * FD + j]; }
#pragma unroll
            for (int k = 0; k < SD; ++k) wC[k] = Wfs[lane * SD + k];
            bA = bgh[lane]; bB = bff[lane];
        } else if (lane < FD + SD) {
            int s = lane - FD;
#pragma unroll
            for (int j = 0; j < FD; ++j) { wA[j] = Wsgf[s * FD + j]; wB[j] = 0.f; }
#pragma unroll
            for (int k = 0; k < SD; ++k) wC[k] = Wsgs[s * SD + k];
            bA = bsgf[s];
        } else {
            int s = lane - 48;
#pragma unroll
            for (int j = 0; j < FD; ++j) { wA[j] = Wsf[s * FD + j]; wB[j] = 0.f; }
#pragma unroll
            for (int k = 0; k < SD; ++k) wC[k] = Wss[s * SD + k];
            bA = bss[s];
        }

        float hf = 0.f, hs = 0.f, pA = 0.f;

        const float* xp = xt + (lane & 31);
        float gx = xp[0], px = xp[FD], fx = xp[64];
        float* sp = states + lane;
        const bool isSlowState = (lane >= FD) && (lane < FD + SD);
        const bool isFast = (lane < FD);
        const bool isST = (lane >= 48);
        const float tsc = isST ? -2.f : -1.f;

        for (int t = 0; t < NSTEP; ++t) {
            // prefetch next xt row (slack rows cover tail; poison loads unused)
            const float* xq = xp + 96;
            float ngx = xq[0], npx = xq[FD], nfx = xq[64];

            // ---- L1: pC = sum_k wC[k] * hs[k]  (hs in lanes 32..47) ----
            float pC;
            {
                float sv[SD];
#pragma unroll
                for (int k = 0; k < SD; ++k) sv[k] = rl(hs, FD + k);
                float a0 = 0.f, a1 = 0.f, a2 = 0.f, a3 = 0.f;
#pragma unroll
                for (int k = 0; k < SD; k += 4) {
                    a0 += wC[k]     * sv[k];
                    a1 += wC[k + 1] * sv[k + 1];
                    a2 += wC[k + 2] * sv[k + 2];
                    a3 += wC[k + 3] * sv[k + 3];
                }
                pC = (a0 + a1) + (a2 + a3);
            }

            // gate (fast lanes): pA = W_gate_h @ hf carried from previous L2
            float ga   = pA + bA + gx;
            float ge   = __expf(-ga);
            float gate = __builtin_amdgcn_rcpf(1.f + ge);
            float hA   = hf + gate * px;

            float c1 = bB + fx + pC;

            // ---- relax 1 ----
            float hB;
            {
                float sv[FD];
#pragma unroll
                for (int j = 0; j < FD; ++j) sv[j] = rl(hA, j);
                float a0 = 0.f, a1 = 0.f, a2 = 0.f, a3 = 0.f;
                float a4 = 0.f, a5 = 0.f, a6 = 0.f, a7 = 0.f;
#pragma unroll
                for (int j = 0; j < FD; j += 8) {
                    a0 += wB[j]     * sv[j];
                    a1 += wB[j + 1] * sv[j + 1];
                    a2 += wB[j + 2] * sv[j + 2];
                    a3 += wB[j + 3] * sv[j + 3];
                    a4 += wB[j + 4] * sv[j + 4];
                    a5 += wB[j + 5] * sv[j + 5];
                    a6 += wB[j + 6] * sv[j + 6];
                    a7 += wB[j + 7] * sv[j + 7];
                }
                float acc = c1 + (((a0 + a1) + (a2 + a3)) + ((a4 + a5) + (a6 + a7)));
                float e  = __expf(-2.f * acc);
                float tg = 2.f * __builtin_amdgcn_rcpf(1.f + e) - 1.f;
                hB = hA + 0.25f * (tg - hA);
            }
            // ---- relax 2 ----
            {
                float sv[FD];
#pragma unroll
                for (int j = 0; j < FD; ++j) sv[j] = rl(hB, j);
                float a0 = 0.f, a1 = 0.f, a2 = 0.f, a3 = 0.f;
                float a4 = 0.f, a5 = 0.f, a6 = 0.f, a7 = 0.f;
#pragma unroll
                for (int j = 0; j < FD; j += 8) {
                    a0 += wB[j]     * sv[j];
                    a1 += wB[j + 1] * sv[j + 1];
                    a2 += wB[j + 2] * sv[j + 2];
                    a3 += wB[j + 3] * sv[j + 3];
                    a4 += wB[j + 4] * sv[j + 4];
                    a5 += wB[j + 5] * sv[j + 5];
                    a6 += wB[j + 6] * sv[j + 6];
                    a7 += wB[j + 7] * sv[j + 7];
                }
                float acc = c1 + (((a0 + a1) + (a2 + a3)) + ((a4 + a5) + (a6 + a7)));
                float e  = __expf(-2.f * acc);
                float tg = 2.f * __builtin_amdgcn_rcpf(1.f + e) - 1.f;
                hf = hB + 0.25f * (tg - hB);
            }

            // ---- L2: pA = sum_j wA[j] * hf_new[j] ----
            {
                float sv[FD];
#pragma unroll
                for (int j = 0; j < FD; ++j) sv[j] = rl(hf, j);
                float a0 = 0.f, a1 = 0.f, a2 = 0.f, a3 = 0.f;
                float a4 = 0.f, a5 = 0.f, a6 = 0.f, a7 = 0.f;
#pragma unroll
                for (int j = 0; j < FD; j += 8) {
                    a0 += wA[j]     * sv[j];
                    a1 += wA[j + 1] * sv[j + 1];
                    a2 += wA[j + 2] * sv[j + 2];
                    a3 += wA[j + 3] * sv[j + 3];
                    a4 += wA[j + 4] * sv[j + 4];
                    a5 += wA[j + 5] * sv[j + 5];
                    a6 += wA[j + 6] * sv[j + 6];
                    a7 += wA[j + 7] * sv[j + 7];
                }
                pA = (((a0 + a1) + (a2 + a3)) + ((a4 + a5) + (a6 + a7)));
            }

            // ---- slow update: lanes 32-47 sigmoid, lanes 48-63 tanh ----
            {
                float u = bA + pC + pA;
                float e = __expf(tsc * u);
                float r = __builtin_amdgcn_rcpf(1.f + e);
                float v = isST ? (2.f * r - 1.f) : r;
                float stv = __shfl(v, lane + 16, 64);
                float hsn = hs + 0.02f * v * (stv - hs);
                hs = isSlowState ? hsn : hs;
            }

            // branchless state store (stride-64 rows)
            sp[0] = isFast ? hf : hs;
            sp += SROW;
            xp += 96;
            gx = ngx; px = npx; fx = nfx;

            // publish progress every 128 steps (release, agent scope)
            if ((t & 127) == 127) {
                __threadfence();
                if (lane == 0)
                    __hip_atomic_store(prog, MAGIC | (t + 1),
                                       __ATOMIC_RELEASE, __HIP_MEMORY_SCOPE_AGENT);
            }
        }
        return;
    }

    // ================= consumers: vocab logits partial expsums =================
    {
        int b = blockIdx.x - 1;          // 0..511
        int chunk = b & (VC - 1);        // 0..31
        int band  = b >> 5;              // 0..15
        int t = band * 256 + threadIdx.x;
        const int needed = band * 256 + 256;

        // wait for scan to pass this band (magic tag defeats ws poison)
        for (;;) {
            int v = __hip_atomic_load(prog, __ATOMIC_ACQUIRE, __HIP_MEMORY_SCOPE_AGENT);
            if (((unsigned)v >> 24) == 0x5Au && (v & 0xFFFFFF) >= needed) break;
            __builtin_amdgcn_s_sleep(32);
        }

        v4f s[12];
        {
            const v4f* q = (const v4f*)(states + (size_t)t * SROW);
#pragma unroll
            for (int k = 0; k < 12; ++k) s[k] = q[k];
        }
        const v2f* s2 = (const v2f*)s;

        int r0 = chunk * ROWS_PER;
        int r1 = min(r0 + ROWS_PER, VOCAB);

        float ssum = 0.f;
        for (int r = r0; r < r1; ++r) {
            const v2f* w = (const v2f*)(Wout + (size_t)r * CD);
            v2f a0 = {0.f,0.f}, a1 = {0.f,0.f}, a2 = {0.f,0.f}, a3 = {0.f,0.f};
#pragma unroll
            for (int k = 0; k < 24; k += 4) {
                a0 += w[k]     * s2[k];
                a1 += w[k + 1] * s2[k + 1];
                a2 += w[k + 2] * s2[k + 2];
                a3 += w[k + 3] * s2[k + 3];
            }
            v2f v = (a0 + a1) + (a2 + a3);
            ssum += __expf(v.x + v.y + bout[r]);    // |logit| < 0.5: max-free safe
        }
        pm[(size_t)t * VC + chunk] = ssum;
    }
}

// ---------------- K3: target logit + per-timestep NLL ----------------
__global__ __launch_bounds__(256) void nll_kernel(
    const int* __restrict__ tok, const float* __restrict__ Wout,
    const float* __restrict__ bout, const float* __restrict__ states,
    const float* __restrict__ pm, float* __restrict__ nll)
{
    int t = blockIdx.x * 256 + threadIdx.x;
    if (t >= NSTEP) return;
    int tgt = tok[t + 1];
    const float* w = Wout + (size_t)tgt * CD;
    float acc = bout[tgt];
#pragma unroll
    for (int k = 0; k < CD; ++k) acc += w[k] * states[(size_t)t * SROW + k];
    const float* p = pm + (size_t)t * VC;
    float ssum = 0.f;
#pragma unroll
    for (int c = 0; c < VC; ++c) ssum += p[c];
    nll[t] = __logf(ssum) - acc;
}

// ---------------- K4: mean reduce ----------------
__global__ __launch_bounds__(256) void reduce_kernel(
    const float* __restrict__ nll, float* __restrict__ out)
{
    __shared__ float red[256];
    float local = 0.f;
    for (int t = threadIdx.x; t < NSTEP; t += 256) local += nll[t];
    red[threadIdx.x] = local;
    __syncthreads();
    for (int off = 128; off > 0; off >>= 1) {
        if (threadIdx.x < off) red[threadIdx.x] += red[threadIdx.x + off];
        __syncthreads();
    }
    if (threadIdx.x == 0) out[0] = red[0] / (float)NSTEP;
}

extern "C" void kernel_launch(void* const* d_in, const int* in_sizes, int n_in,
                              void* d_out, int out_size, void* d_ws, size_t ws_size,
                              hipStream_t stream) {
    const int*   tok   = (const int*)  d_in[0];
    const float* embed = (const float*)d_in[1];
    const float* Wgh   = (const float*)d_in[2];
    const float* bgh   = (const float*)d_in[3];
    const float* Wgx   = (const float*)d_in[4];
    const float* Wxp   = (const float*)d_in[5];
    const float* Wff   = (const float*)d_in[6];
    const float* bff   = (const float*)d_in[7];
    const float* Wfs   = (const float*)d_in[8];
    const float* Wxf   = (const float*)d_in[9];
    const float* Wsgf  = (const float*)d_in[10];
    const float* bsgf  = (const float*)d_in[11];
    const float* Wsgs  = (const float*)d_in[12];
    const float* Wss   = (const float*)d_in[13];
    const float* bss   = (const float*)d_in[14];
    const float* Wsf   = (const float*)d_in[15];
    const float* Wout  = (const float*)d_in[16];
    const float* bout  = (const float*)d_in[17];

    float* ws     = (float*)d_ws;
    float* xt     = ws + WS_XT;
    float* states = ws + WS_STATES;
    float* pm     = ws + WS_PM;
    float* nll    = ws + WS_NLL;
    int*   prog   = (int*)(ws + WS_PROG);
    float* outf   = (float*)d_out;

    xterm_kernel<<<dim3(NSTEP / 8), dim3(256), 0, stream>>>(tok, embed, Wgx, Wxp, Wxf, xt);
    fused_kernel<<<dim3(1 + VC * NBAND), dim3(256), 0, stream>>>(
        Wgh, bgh, Wff, bff, Wfs, Wsgf, bsgf, Wsgs, Wss, bss, Wsf,
        xt, states, Wout, bout, pm, prog);
    nll_kernel<<<dim3(NSTEP / 256), dim3(256), 0, stream>>>(tok, Wout, bout, states, pm, nll);
    reduce_kernel<<<dim3(1), dim3(256), 0, stream>>>(nll, outf);
}

// Round 7
// 5440.445 us; speedup vs baseline: 18.3205x; 18.3205x over previous
//
#include <hip/hip_runtime.h>
#include <hip/hip_bf16.h>
#include <cmath>

#define FD 32
#define SD 16
#define NSTEP 4096
#define VOCAB 50257
#define CD 48            // FD + SD (logical)
#define SROW 64          // states row stride (padded; rows 256B-aligned)
#define VC 64            // vocab chunks for logits pass
#define ROWS_PER ((VOCAB + VC - 1) / VC)   // 786
#define XSLACK 2         // xt slack rows for prefetch

typedef float v2f __attribute__((ext_vector_type(2)));

// ---------------- workspace layout (floats) ----------------
#define WS_XT     0
#define WS_STATES ((NSTEP + XSLACK) * 96)
#define WS_PM     (WS_STATES + NSTEP * SROW)
#define WS_TL     (WS_PM + NSTEP * VC)
#define WS_NLL    (WS_TL + NSTEP)

__device__ __forceinline__ float rl(float v, int l) {
    return __builtin_bit_cast(float, __builtin_amdgcn_readlane(__builtin_bit_cast(int, v), l));
}
__device__ __forceinline__ float bperm(int byteaddr, float v) {
    return __builtin_bit_cast(float, __builtin_amdgcn_ds_bpermute(byteaddr, __builtin_bit_cast(int, v)));
}

// ---------------- K1: precompute token-dependent terms ----------------
__global__ __launch_bounds__(256) void xterm_kernel(
    const int* __restrict__ tok, const float* __restrict__ embed,
    const float* __restrict__ Wgx, const float* __restrict__ Wxp,
    const float* __restrict__ Wxf, float* __restrict__ xt)
{
    int t = blockIdx.x * 8 + (threadIdx.x >> 5);
    int i = threadIdx.x & 31;
    if (t >= NSTEP) return;
    const float* x = embed + (size_t)tok[t] * FD;
    float a0 = 0.f, a1 = 0.f, a2 = 0.f;
#pragma unroll
    for (int j = 0; j < FD; ++j) {
        float xj = x[j];
        a0 += Wgx[i * FD + j] * xj;
        a1 += Wxp[i * FD + j] * xj;
        a2 += Wxf[i * FD + j] * xj;
    }
    xt[t * 96 + i]      = a0;
    xt[t * 96 + 32 + i] = a1;
    xt[t * 96 + 64 + i] = a2;
}

// ---------------- K2: serial scan — readlane broadcast + half-wave-split relax ----
// Lane layout:
//   lanes  0-31 (i): rows of W_gate_h (wA), W_fs (wC); W_ff[i][0:16] (wB16); hf[i]
//   lanes 32-47 (s): rows of W_sg_f (wA), W_sg_s (wC); W_ff[lane-32][16:32]; hs[s]
//   lanes 48-63 (s): rows of W_sf   (wA), W_ss   (wC); W_ff[lane-32][16:32]
// Relax matvecs split K across half-waves: lane i sums j=0..15, lane i+32 sums
// j=16..31 of the SAME output row i; sources broadcast via ds_bpermute (lower
// half reads lanes 0..15, upper half lanes 16..31 — <=2 distinct sources per
// op = conflict-free); one bpermute(lane^32) combines partials.
// L1/L2 keep the R3 readlane form (all 64 lanes productive there).
__global__ __launch_bounds__(64) void scan_kernel(
    const float* __restrict__ Wgh, const float* __restrict__ bgh,
    const float* __restrict__ Wff, const float* __restrict__ bff,
    const float* __restrict__ Wfs,
    const float* __restrict__ Wsgf, const float* __restrict__ bsgf,
    const float* __restrict__ Wsgs, const float* __restrict__ Wss,
    const float* __restrict__ bss, const float* __restrict__ Wsf,
    const float* __restrict__ xt, float* __restrict__ states)
{
    const int lane = threadIdx.x;
    float wA[FD], wC[SD], wB16[16];
    float bA = 0.f, bB = 0.f;

    // relax half-row: lanes 0-31 -> W_ff[lane][0:16]; lanes 32-63 -> W_ff[lane-32][16:32]
    {
        int row = lane & 31;
        int col0 = (lane >> 5) << 4;
#pragma unroll
        for (int k = 0; k < 16; ++k) wB16[k] = Wff[row * FD + col0 + k];
    }

    if (lane < FD) {
#pragma unroll
        for (int j = 0; j < FD; ++j) wA[j] = Wgh[lane * FD + j];
#pragma unroll
        for (int k = 0; k < SD; ++k) wC[k] = Wfs[lane * SD + k];
        bA = bgh[lane]; bB = bff[lane];
    } else if (lane < FD + SD) {
        int s = lane - FD;
#pragma unroll
        for (int j = 0; j < FD; ++j) wA[j] = Wsgf[s * FD + j];
#pragma unroll
        for (int k = 0; k < SD; ++k) wC[k] = Wsgs[s * SD + k];
        bA = bsgf[s];
    } else {
        int s = lane - 48;
#pragma unroll
        for (int j = 0; j < FD; ++j) wA[j] = Wsf[s * FD + j];
#pragma unroll
        for (int k = 0; k < SD; ++k) wC[k] = Wss[s * SD + k];
        bA = bss[s];
    }

    float hf = 0.f, hs = 0.f, pA = 0.f;

    const int bp_base = ((lane >> 5) << 4) * 4;   // byte addr: lane 0 or 16
    const int bp_comb = (lane ^ 32) * 4;          // partner half-wave lane

    const float* xp = xt + (lane & 31);
    float gx = xp[0], px = xp[FD], fx = xp[64];
    float* sp = states + lane;
    const bool isSlowState = (lane >= FD) && (lane < FD + SD);
    const bool isFast = (lane < FD);
    const bool isST = (lane >= 48);
    const float tsc = isST ? -2.f : -1.f;

    for (int t = 0; t < NSTEP; ++t) {
        // prefetch next xt row (slack rows cover tail; unused tail loads harmless)
        const float* xq = xp + 96;
        float ngx = xq[0], npx = xq[FD], nfx = xq[64];

        // ---- L1: pC = sum_k wC[k] * hs[k]  (hs in lanes 32..47) ----
        float pC;
        {
            float sv[SD];
#pragma unroll
            for (int k = 0; k < SD; ++k) sv[k] = rl(hs, FD + k);
            float a0 = 0.f, a1 = 0.f, a2 = 0.f, a3 = 0.f;
#pragma unroll
            for (int k = 0; k < SD; k += 4) {
                a0 += wC[k]     * sv[k];
                a1 += wC[k + 1] * sv[k + 1];
                a2 += wC[k + 2] * sv[k + 2];
                a3 += wC[k + 3] * sv[k + 3];
            }
            pC = (a0 + a1) + (a2 + a3);
        }

        // gate (fast lanes): pA = W_gate_h @ hf carried from previous L2
        float ga   = pA + bA + gx;
        float ge   = __expf(-ga);
        float gate = __builtin_amdgcn_rcpf(1.f + ge);
        float hA   = hf + gate * px;

        float c1 = bB + fx + pC;

        // ---- relax 1 (half-wave K-split) ----
        float hB;
        {
            float sv[16];
#pragma unroll
            for (int k = 0; k < 16; ++k) sv[k] = bperm(bp_base + 4 * k, hA);
            float a0 = 0.f, a1 = 0.f, a2 = 0.f, a3 = 0.f;
#pragma unroll
            for (int k = 0; k < 16; k += 4) {
                a0 += wB16[k]     * sv[k];
                a1 += wB16[k + 1] * sv[k + 1];
                a2 += wB16[k + 2] * sv[k + 2];
                a3 += wB16[k + 3] * sv[k + 3];
            }
            float part = (a0 + a1) + (a2 + a3);
            float other = bperm(bp_comb, part);
            float acc = c1 + (part + other);
            float e  = __expf(-2.f * acc);
            float tg = 2.f * __builtin_amdgcn_rcpf(1.f + e) - 1.f;
            hB = hA + 0.25f * (tg - hA);
        }
        // ---- relax 2 (half-wave K-split) ----
        {
            float sv[16];
#pragma unroll
            for (int k = 0; k < 16; ++k) sv[k] = bperm(bp_base + 4 * k, hB);
            float a0 = 0.f, a1 = 0.f, a2 = 0.f, a3 = 0.f;
#pragma unroll
            for (int k = 0; k < 16; k += 4) {
                a0 += wB16[k]     * sv[k];
                a1 += wB16[k + 1] * sv[k + 1];
                a2 += wB16[k + 2] * sv[k + 2];
                a3 += wB16[k + 3] * sv[k + 3];
            }
            float part = (a0 + a1) + (a2 + a3);
            float other = bperm(bp_comb, part);
            float acc = c1 + (part + other);
            float e  = __expf(-2.f * acc);
            float tg = 2.f * __builtin_amdgcn_rcpf(1.f + e) - 1.f;
            hf = hB + 0.25f * (tg - hB);
        }

        // ---- L2: pA = sum_j wA[j] * hf_new[j] (readlane; all lanes productive) ----
        {
            float sv[FD];
#pragma unroll
            for (int j = 0; j < FD; ++j) sv[j] = rl(hf, j);
            float a0 = 0.f, a1 = 0.f, a2 = 0.f, a3 = 0.f;
            float a4 = 0.f, a5 = 0.f, a6 = 0.f, a7 = 0.f;
#pragma unroll
            for (int j = 0; j < FD; j += 8) {
                a0 += wA[j]     * sv[j];
                a1 += wA[j + 1] * sv[j + 1];
                a2 += wA[j + 2] * sv[j + 2];
                a3 += wA[j + 3] * sv[j + 3];
                a4 += wA[j + 4] * sv[j + 4];
                a5 += wA[j + 5] * sv[j + 5];
                a6 += wA[j + 6] * sv[j + 6];
                a7 += wA[j + 7] * sv[j + 7];
            }
            pA = (((a0 + a1) + (a2 + a3)) + ((a4 + a5) + (a6 + a7)));
        }

        // ---- slow update: lanes 32-47 sigmoid, lanes 48-63 tanh ----
        {
            float u = bA + pC + pA;
            float e = __expf(tsc * u);
            float r = __builtin_amdgcn_rcpf(1.f + e);
            float v = isST ? (2.f * r - 1.f) : r;
            float stv = __shfl(v, lane + 16, 64);
            float hsn = hs + 0.02f * v * (stv - hs);
            hs = isSlowState ? hsn : hs;
        }

        // branchless state store (stride-64 rows; slots 48-63 stay zero)
        sp[0] = isFast ? hf : hs;
        sp += SROW;
        xp += 96;
        gx = ngx; px = npx; fx = nfx;
    }
}

// ---------------- K3: vocab logits + per-chunk sumexp (max-free) ----------------
// |logit| < 0.5 (xavier gain 0.5, bounded state) -> plain exp-sum is safe.
__global__ __launch_bounds__(256) void logits_kernel(
    const float* __restrict__ Wout, const float* __restrict__ bout,
    const float* __restrict__ states, float* __restrict__ pm)
{
    int tb = blockIdx.y * 512 + threadIdx.x;     // t0 = tb, t1 = tb + 256
    int chunk = blockIdx.x;
    int r0 = chunk * ROWS_PER;
    int r1 = min(r0 + ROWS_PER, VOCAB);

    v2f s0[24], s1[24];
    {
        const v2f* q0 = (const v2f*)(states + (size_t)tb * SROW);
        const v2f* q1 = (const v2f*)(states + (size_t)(tb + 256) * SROW);
#pragma unroll
        for (int k = 0; k < 24; ++k) { s0[k] = q0[k]; s1[k] = q1[k]; }
    }

    float sx = 0.f, sy = 0.f;
    for (int r = r0; r < r1; ++r) {
        const v2f* w = (const v2f*)(Wout + (size_t)r * CD);
        v2f a0 = {0.f,0.f}, b0 = {0.f,0.f}, a1 = {0.f,0.f}, b1 = {0.f,0.f};
#pragma unroll
        for (int k = 0; k < 24; k += 2) {
            v2f wk0 = w[k], wk1 = w[k + 1];
            a0 += wk0 * s0[k];
            a1 += wk0 * s1[k];
            b0 += wk1 * s0[k + 1];
            b1 += wk1 * s1[k + 1];
        }
        v2f v0 = a0 + b0, v1 = a1 + b1;
        float bo = bout[r];
        sx += __expf(v0.x + v0.y + bo);
        sy += __expf(v1.x + v1.y + bo);
    }
    pm[(size_t)tb * VC + chunk]         = sx;
    pm[(size_t)(tb + 256) * VC + chunk] = sy;
}

// ---------------- K4: target logits ----------------
__global__ __launch_bounds__(256) void tlogit_kernel(
    const int* __restrict__ tok, const float* __restrict__ Wout,
    const float* __restrict__ bout, const float* __restrict__ states,
    float* __restrict__ tl)
{
    int t = blockIdx.x * 256 + threadIdx.x;
    if (t >= NSTEP) return;
    int tgt = tok[t + 1];
    const float* w = Wout + (size_t)tgt * CD;
    float acc = bout[tgt];
#pragma unroll
    for (int k = 0; k < CD; ++k) acc += w[k] * states[(size_t)t * SROW + k];
    tl[t] = acc;
}

// ---------------- K5a: per-timestep NLL ----------------
__global__ __launch_bounds__(256) void nll_kernel(
    const float* __restrict__ pm, const float* __restrict__ tl,
    float* __restrict__ nll)
{
    int t = blockIdx.x * 256 + threadIdx.x;
    const float* p = pm + (size_t)t * VC;
    float ssum = 0.f;
#pragma unroll
    for (int c = 0; c < VC; ++c) ssum += p[c];
    nll[t] = __logf(ssum) - tl[t];
}

// ---------------- K5b: mean reduce ----------------
__global__ __launch_bounds__(256) void reduce_kernel(
    const float* __restrict__ nll, float* __restrict__ out)
{
    __shared__ float red[256];
    float local = 0.f;
    for (int t = threadIdx.x; t < NSTEP; t += 256) local += nll[t];
    red[threadIdx.x] = local;
    __syncthreads();
    for (int off = 128; off > 0; off >>= 1) {
        if (threadIdx.x < off) red[threadIdx.x] += red[threadIdx.x + off];
        __syncthreads();
    }
    if (threadIdx.x == 0) out[0] = red[0] / (float)NSTEP;
}

extern "C" void kernel_launch(void* const* d_in, const int* in_sizes, int n_in,
                              void* d_out, int out_size, void* d_ws, size_t ws_size,
                              hipStream_t stream) {
    const int*   tok   = (const int*)  d_in[0];
    const float* embed = (const float*)d_in[1];
    const float* Wgh   = (const float*)d_in[2];
    const float* bgh   = (const float*)d_in[3];
    const float* Wgx   = (const float*)d_in[4];
    const float* Wxp   = (const float*)d_in[5];
    const float* Wff   = (const float*)d_in[6];
    const float* bff   = (const float*)d_in[7];
    const float* Wfs   = (const float*)d_in[8];
    const float* Wxf   = (const float*)d_in[9];
    const float* Wsgf  = (const float*)d_in[10];
    const float* bsgf  = (const float*)d_in[11];
    const float* Wsgs  = (const float*)d_in[12];
    const float* Wss   = (const float*)d_in[13];
    const float* bss   = (const float*)d_in[14];
    const float* Wsf   = (const float*)d_in[15];
    const float* Wout  = (const float*)d_in[16];
    const float* bout  = (const float*)d_in[17];

    float* ws     = (float*)d_ws;
    float* xt     = ws + WS_XT;
    float* states = ws + WS_STATES;
    float* pm     = ws + WS_PM;
    float* tl     = ws + WS_TL;
    float* nll    = ws + WS_NLL;
    float* outf   = (float*)d_out;

    xterm_kernel<<<dim3(NSTEP / 8), dim3(256), 0, stream>>>(tok, embed, Wgx, Wxp, Wxf, xt);
    scan_kernel<<<dim3(1), dim3(64), 0, stream>>>(Wgh, bgh, Wff, bff, Wfs, Wsgf, bsgf,
                                                  Wsgs, Wss, bss, Wsf, xt, states);
    logits_kernel<<<dim3(VC, NSTEP / 512), dim3(256), 0, stream>>>(Wout, bout, states, pm);
    tlogit_kernel<<<dim3(NSTEP / 256), dim3(256), 0, stream>>>(tok, Wout, bout, states, tl);
    nll_kernel<<<dim3(NSTEP / 256), dim3(256), 0, stream>>>(pm, tl, nll);
    reduce_kernel<<<dim3(1), dim3(256), 0, stream>>>(nll, outf);
}

// Round 8
// 2778.697 us; speedup vs baseline: 35.8699x; 1.9579x over previous
//
#include <hip/hip_runtime.h>
#include <hip/hip_bf16.h>
#include <cmath>

#define FD 32
#define SD 16
#define NSTEP 4096
#define VOCAB 50257
#define CD 48            // FD + SD (logical)
#define SROW 64          // states row stride (padded; rows 256B-aligned)
#define VC 64            // vocab chunks for logits pass
#define ROWS_PER ((VOCAB + VC - 1) / VC)   // 786
#define XSLACK 2         // xt slack rows for prefetch

typedef float v2f __attribute__((ext_vector_type(2)));

// ---------------- workspace layout (floats) ----------------
#define WS_XT     0
#define WS_STATES ((NSTEP + XSLACK) * 96)
#define WS_PM     (WS_STATES + NSTEP * SROW)
#define WS_TL     (WS_PM + NSTEP * VC)
#define WS_NLL    (WS_TL + NSTEP)

__device__ __forceinline__ float rl(float v, int l) {
    return __builtin_bit_cast(float, __builtin_amdgcn_readlane(__builtin_bit_cast(int, v), l));
}

// ---------------- K1: precompute token-dependent terms ----------------
__global__ __launch_bounds__(256) void xterm_kernel(
    const int* __restrict__ tok, const float* __restrict__ embed,
    const float* __restrict__ Wgx, const float* __restrict__ Wxp,
    const float* __restrict__ Wxf, float* __restrict__ xt)
{
    int t = blockIdx.x * 8 + (threadIdx.x >> 5);
    int i = threadIdx.x & 31;
    if (t >= NSTEP) return;
    const float* x = embed + (size_t)tok[t] * FD;
    float a0 = 0.f, a1 = 0.f, a2 = 0.f;
#pragma unroll
    for (int j = 0; j < FD; ++j) {
        float xj = x[j];
        a0 += Wgx[i * FD + j] * xj;
        a1 += Wxp[i * FD + j] * xj;
        a2 += Wxf[i * FD + j] * xj;
    }
    xt[t * 96 + i]      = a0;
    xt[t * 96 + 32 + i] = a1;
    xt[t * 96 + 64 + i] = a2;
}

// ---------------- K2: serial scan — readlane pairs + packed fp32 FMA ----------------
// Lane layout (R3 structure, measured best):
//   lanes  0-31 (i): rows of W_gate_h (wA2), W_ff (wB2), W_fs (wC2); hf[i]
//   lanes 32-47 (s): rows of W_sg_f (wA2), W_sg_s (wC2); hs[s]
//   lanes 48-63 (s): rows of W_sf   (wA2), W_ss   (wC2)
// Broadcasts: v_readlane pairs packed into float2 (wave-uniform -> SGPR pair),
// consumed by v2f FMA -> v_pk_fma_f32 (2 MACs / instr). Single wave: no LDS,
// no barriers, no DS-pipe ops in the loop except the one slow-update shfl.
__global__ __launch_bounds__(64) void scan_kernel(
    const float* __restrict__ Wgh, const float* __restrict__ bgh,
    const float* __restrict__ Wff, const float* __restrict__ bff,
    const float* __restrict__ Wfs,
    const float* __restrict__ Wsgf, const float* __restrict__ bsgf,
    const float* __restrict__ Wsgs, const float* __restrict__ Wss,
    const float* __restrict__ bss, const float* __restrict__ Wsf,
    const float* __restrict__ xt, float* __restrict__ states)
{
    const int lane = threadIdx.x;
    v2f wA2[16], wB2[16], wC2[8];
    float bA = 0.f, bB = 0.f;

    if (lane < FD) {
        const v2f* a = (const v2f*)(Wgh + lane * FD);
        const v2f* b = (const v2f*)(Wff + lane * FD);
#pragma unroll
        for (int j = 0; j < 16; ++j) { wA2[j] = a[j]; wB2[j] = b[j]; }
        const v2f* c = (const v2f*)(Wfs + lane * SD);
#pragma unroll
        for (int k = 0; k < 8; ++k) wC2[k] = c[k];
        bA = bgh[lane]; bB = bff[lane];
    } else if (lane < FD + SD) {
        int s = lane - FD;
        const v2f* a = (const v2f*)(Wsgf + s * FD);
#pragma unroll
        for (int j = 0; j < 16; ++j) { wA2[j] = a[j]; wB2[j] = (v2f){0.f, 0.f}; }
        const v2f* c = (const v2f*)(Wsgs + s * SD);
#pragma unroll
        for (int k = 0; k < 8; ++k) wC2[k] = c[k];
        bA = bsgf[s];
    } else {
        int s = lane - 48;
        const v2f* a = (const v2f*)(Wsf + s * FD);
#pragma unroll
        for (int j = 0; j < 16; ++j) { wA2[j] = a[j]; wB2[j] = (v2f){0.f, 0.f}; }
        const v2f* c = (const v2f*)(Wss + s * SD);
#pragma unroll
        for (int k = 0; k < 8; ++k) wC2[k] = c[k];
        bA = bss[s];
    }

    float hf = 0.f, hs = 0.f, pA = 0.f;

    const float* xp = xt + (lane & 31);
    float gx = xp[0], px = xp[FD], fx = xp[64];
    float* sp = states + lane;
    const bool isSlowState = (lane >= FD) && (lane < FD + SD);
    const bool isFast = (lane < FD);
    const bool isST = (lane >= 48);
    const float tsc = isST ? -2.f : -1.f;

    for (int t = 0; t < NSTEP; ++t) {
        // prefetch next xt row (slack rows cover tail; tail loads unused)
        const float* xq = xp + 96;
        float ngx = xq[0], npx = xq[FD], nfx = xq[64];

        // ---- L1: pC = sum_k wC[k] * hs[k]  (hs in lanes 32..47) ----
        float pC;
        {
            v2f sv[8];
#pragma unroll
            for (int k = 0; k < 8; ++k)
                sv[k] = (v2f){rl(hs, FD + 2 * k), rl(hs, FD + 2 * k + 1)};
            v2f a0 = {0.f,0.f}, a1 = {0.f,0.f}, a2 = {0.f,0.f}, a3 = {0.f,0.f};
            a0 += wC2[0] * sv[0]; a1 += wC2[1] * sv[1];
            a2 += wC2[2] * sv[2]; a3 += wC2[3] * sv[3];
            a0 += wC2[4] * sv[4]; a1 += wC2[5] * sv[5];
            a2 += wC2[6] * sv[6]; a3 += wC2[7] * sv[7];
            v2f r = (a0 + a1) + (a2 + a3);
            pC = r.x + r.y;
        }

        // gate (fast lanes): pA = W_gate_h @ hf carried from previous L2
        float ga   = pA + bA + gx;
        float ge   = __expf(-ga);
        float gate = __builtin_amdgcn_rcpf(1.f + ge);
        float hA   = hf + gate * px;

        float c1 = bB + fx + pC;

        // ---- relax 1 ----
        float hB;
        {
            v2f sv[16];
#pragma unroll
            for (int j = 0; j < 16; ++j)
                sv[j] = (v2f){rl(hA, 2 * j), rl(hA, 2 * j + 1)};
            v2f a0 = {0.f,0.f}, a1 = {0.f,0.f}, a2 = {0.f,0.f}, a3 = {0.f,0.f};
#pragma unroll
            for (int j = 0; j < 16; j += 4) {
                a0 += wB2[j]     * sv[j];
                a1 += wB2[j + 1] * sv[j + 1];
                a2 += wB2[j + 2] * sv[j + 2];
                a3 += wB2[j + 3] * sv[j + 3];
            }
            v2f r = (a0 + a1) + (a2 + a3);
            float acc = c1 + r.x + r.y;
            float e  = __expf(-2.f * acc);
            float tg = 2.f * __builtin_amdgcn_rcpf(1.f + e) - 1.f;
            hB = hA + 0.25f * (tg - hA);
        }
        // ---- relax 2 ----
        {
            v2f sv[16];
#pragma unroll
            for (int j = 0; j < 16; ++j)
                sv[j] = (v2f){rl(hB, 2 * j), rl(hB, 2 * j + 1)};
            v2f a0 = {0.f,0.f}, a1 = {0.f,0.f}, a2 = {0.f,0.f}, a3 = {0.f,0.f};
#pragma unroll
            for (int j = 0; j < 16; j += 4) {
                a0 += wB2[j]     * sv[j];
                a1 += wB2[j + 1] * sv[j + 1];
                a2 += wB2[j + 2] * sv[j + 2];
                a3 += wB2[j + 3] * sv[j + 3];
            }
            v2f r = (a0 + a1) + (a2 + a3);
            float acc = c1 + r.x + r.y;
            float e  = __expf(-2.f * acc);
            float tg = 2.f * __builtin_amdgcn_rcpf(1.f + e) - 1.f;
            hf = hB + 0.25f * (tg - hB);
        }

        // ---- L2: pA = sum_j wA[j] * hf_new[j] ----
        {
            v2f sv[16];
#pragma unroll
            for (int j = 0; j < 16; ++j)
                sv[j] = (v2f){rl(hf, 2 * j), rl(hf, 2 * j + 1)};
            v2f a0 = {0.f,0.f}, a1 = {0.f,0.f}, a2 = {0.f,0.f}, a3 = {0.f,0.f};
#pragma unroll
            for (int j = 0; j < 16; j += 4) {
                a0 += wA2[j]     * sv[j];
                a1 += wA2[j + 1] * sv[j + 1];
                a2 += wA2[j + 2] * sv[j + 2];
                a3 += wA2[j + 3] * sv[j + 3];
            }
            v2f r = (a0 + a1) + (a2 + a3);
            pA = r.x + r.y;
        }

        // ---- slow update: lanes 32-47 sigmoid, lanes 48-63 tanh ----
        {
            float u = bA + pC + pA;
            float e = __expf(tsc * u);
            float r = __builtin_amdgcn_rcpf(1.f + e);
            float v = isST ? (2.f * r - 1.f) : r;
            float stv = __shfl(v, lane + 16, 64);
            float hsn = hs + 0.02f * v * (stv - hs);
            hs = isSlowState ? hsn : hs;
        }

        // branchless state store (stride-64 rows)
        sp[0] = isFast ? hf : hs;
        sp += SROW;
        xp += 96;
        gx = ngx; px = npx; fx = nfx;
    }
}

// ---------------- K3: vocab logits + per-chunk sumexp (max-free) ----------------
// |logit| < 0.5 (xavier gain 0.5, bounded state) -> plain exp-sum is safe.
__global__ __launch_bounds__(256) void logits_kernel(
    const float* __restrict__ Wout, const float* __restrict__ bout,
    const float* __restrict__ states, float* __restrict__ pm)
{
    int tb = blockIdx.y * 512 + threadIdx.x;     // t0 = tb, t1 = tb + 256
    int chunk = blockIdx.x;
    int r0 = chunk * ROWS_PER;
    int r1 = min(r0 + ROWS_PER, VOCAB);

    v2f s0[24], s1[24];
    {
        const v2f* q0 = (const v2f*)(states + (size_t)tb * SROW);
        const v2f* q1 = (const v2f*)(states + (size_t)(tb + 256) * SROW);
#pragma unroll
        for (int k = 0; k < 24; ++k) { s0[k] = q0[k]; s1[k] = q1[k]; }
    }

    float sx = 0.f, sy = 0.f;
    for (int r = r0; r < r1; ++r) {
        const v2f* w = (const v2f*)(Wout + (size_t)r * CD);
        v2f a0 = {0.f,0.f}, b0 = {0.f,0.f}, a1 = {0.f,0.f}, b1 = {0.f,0.f};
#pragma unroll
        for (int k = 0; k < 24; k += 2) {
            v2f wk0 = w[k], wk1 = w[k + 1];
            a0 += wk0 * s0[k];
            a1 += wk0 * s1[k];
            b0 += wk1 * s0[k + 1];
            b1 += wk1 * s1[k + 1];
        }
        v2f v0 = a0 + b0, v1 = a1 + b1;
        float bo = bout[r];
        sx += __expf(v0.x + v0.y + bo);
        sy += __expf(v1.x + v1.y + bo);
    }
    pm[(size_t)tb * VC + chunk]         = sx;
    pm[(size_t)(tb + 256) * VC + chunk] = sy;
}

// ---------------- K4: target logits ----------------
__global__ __launch_bounds__(256) void tlogit_kernel(
    const int* __restrict__ tok, const float* __restrict__ Wout,
    const float* __restrict__ bout, const float* __restrict__ states,
    float* __restrict__ tl)
{
    int t = blockIdx.x * 256 + threadIdx.x;
    if (t >= NSTEP) return;
    int tgt = tok[t + 1];
    const float* w = Wout + (size_t)tgt * CD;
    float acc = bout[tgt];
#pragma unroll
    for (int k = 0; k < CD; ++k) acc += w[k] * states[(size_t)t * SROW + k];
    tl[t] = acc;
}

// ---------------- K5a: per-timestep NLL ----------------
__global__ __launch_bounds__(256) void nll_kernel(
    const float* __restrict__ pm, const float* __restrict__ tl,
    float* __restrict__ nll)
{
    int t = blockIdx.x * 256 + threadIdx.x;
    const float* p = pm + (size_t)t * VC;
    float ssum = 0.f;
#pragma unroll
    for (int c = 0; c < VC; ++c) ssum += p[c];
    nll[t] = __logf(ssum) - tl[t];
}

// ---------------- K5b: mean reduce ----------------
__global__ __launch_bounds__(256) void reduce_kernel(
    const float* __restrict__ nll, float* __restrict__ out)
{
    __shared__ float red[256];
    float local = 0.f;
    for (int t = threadIdx.x; t < NSTEP; t += 256) local += nll[t];
    red[threadIdx.x] = local;
    __syncthreads();
    for (int off = 128; off > 0; off >>= 1) {
        if (threadIdx.x < off) red[threadIdx.x] += red[threadIdx.x + off];
        __syncthreads();
    }
    if (threadIdx.x == 0) out[0] = red[0] / (float)NSTEP;
}

extern "C" void kernel_launch(void* const* d_in, const int* in_sizes, int n_in,
                              void* d_out, int out_size, void* d_ws, size_t ws_size,
                              hipStream_t stream) {
    const int*   tok   = (const int*)  d_in[0];
    const float* embed = (const float*)d_in[1];
    const float* Wgh   = (const float*)d_in[2];
    const float* bgh   = (const float*)d_in[3];
    const float* Wgx   = (const float*)d_in[4];
    const float* Wxp   = (const float*)d_in[5];
    const float* Wff   = (const float*)d_in[6];
    const float* bff   = (const float*)d_in[7];
    const float* Wfs   = (const float*)d_in[8];
    const float* Wxf   = (const float*)d_in[9];
    const float* Wsgf  = (const float*)d_in[10];
    const float* bsgf  = (const float*)d_in[11];
    const float* Wsgs  = (const float*)d_in[12];
    const float* Wss   = (const float*)d_in[13];
    const float* bss   = (const float*)d_in[14];
    const float* Wsf   = (const float*)d_in[15];
    const float* Wout  = (const float*)d_in[16];
    const float* bout  = (const float*)d_in[17];

    float* ws     = (float*)d_ws;
    float* xt     = ws + WS_XT;
    float* states = ws + WS_STATES;
    float* pm     = ws + WS_PM;
    float* tl     = ws + WS_TL;
    float* nll    = ws + WS_NLL;
    float* outf   = (float*)d_out;

    xterm_kernel<<<dim3(NSTEP / 8), dim3(256), 0, stream>>>(tok, embed, Wgx, Wxp, Wxf, xt);
    scan_kernel<<<dim3(1), dim3(64), 0, stream>>>(Wgh, bgh, Wff, bff, Wfs, Wsgf, bsgf,
                                                  Wsgs, Wss, bss, Wsf, xt, states);
    logits_kernel<<<dim3(VC, NSTEP / 512), dim3(256), 0, stream>>>(Wout, bout, states, pm);
    tlogit_kernel<<<dim3(NSTEP / 256), dim3(256), 0, stream>>>(tok, Wout, bout, states, tl);
    nll_kernel<<<dim3(NSTEP / 256), dim3(256), 0, stream>>>(pm, tl, nll);
    reduce_kernel<<<dim3(1), dim3(256), 0, stream>>>(nll, outf);
}

// Round 9
// 2447.794 us; speedup vs baseline: 40.7190x; 1.1352x over previous
//
#include <hip/hip_runtime.h>
#include <hip/hip_bf16.h>
#include <cmath>

#define FD 32
#define SD 16
#define NSTEP 4096
#define NSP (NSTEP + 8)  // xt plane stride (slack for 4-step prefetch; 16B-aligned)
#define VOCAB 50257
#define CD 48            // FD + SD (logical)
#define SROW 64          // states row stride (padded; rows 256B-aligned)
#define VC 64            // vocab chunks for logits pass
#define ROWS_PER ((VOCAB + VC - 1) / VC)   // 786
#define TR 128           // logits LDS tile rows

typedef float v2f __attribute__((ext_vector_type(2)));
typedef float v4f __attribute__((ext_vector_type(4)));

// ---------------- workspace layout (floats) ----------------
// xt transposed: [3][32][NSP]  (plane p, lane i, time t)
#define WS_XT     0
#define WS_STATES (96 * NSP)
#define WS_PM     (WS_STATES + NSTEP * SROW)
#define WS_NLL    (WS_PM + NSTEP * VC)

__device__ __forceinline__ float rl(float v, int l) {
    return __builtin_bit_cast(float, __builtin_amdgcn_readlane(__builtin_bit_cast(int, v), l));
}

// ---------------- K1: precompute token-dependent terms (transposed store) ----------------
__global__ __launch_bounds__(256) void xterm_kernel(
    const int* __restrict__ tok, const float* __restrict__ embed,
    const float* __restrict__ Wgx, const float* __restrict__ Wxp,
    const float* __restrict__ Wxf, float* __restrict__ xt)
{
    int t = blockIdx.x * 8 + (threadIdx.x >> 5);
    int i = threadIdx.x & 31;
    if (t >= NSTEP) return;
    const float* x = embed + (size_t)tok[t] * FD;
    float a0 = 0.f, a1 = 0.f, a2 = 0.f;
#pragma unroll
    for (int j = 0; j < FD; ++j) {
        float xj = x[j];
        a0 += Wgx[i * FD + j] * xj;
        a1 += Wxp[i * FD + j] * xj;
        a2 += Wxf[i * FD + j] * xj;
    }
    xt[(0 * 32 + i) * NSP + t] = a0;
    xt[(1 * 32 + i) * NSP + t] = a1;
    xt[(2 * 32 + i) * NSP + t] = a2;
}

// ---------------- K2: serial scan — readlane pairs + packed fp32 FMA ----------------
// R8 structure (measured best) + transposed-xt dwordx4 loads (3 loads / 4 steps).
__global__ __launch_bounds__(64) void scan_kernel(
    const float* __restrict__ Wgh, const float* __restrict__ bgh,
    const float* __restrict__ Wff, const float* __restrict__ bff,
    const float* __restrict__ Wfs,
    const float* __restrict__ Wsgf, const float* __restrict__ bsgf,
    const float* __restrict__ Wsgs, const float* __restrict__ Wss,
    const float* __restrict__ bss, const float* __restrict__ Wsf,
    const float* __restrict__ xt, float* __restrict__ states)
{
    const int lane = threadIdx.x;
    v2f wA2[16], wB2[16], wC2[8];
    float bA = 0.f, bB = 0.f;

    if (lane < FD) {
        const v2f* a = (const v2f*)(Wgh + lane * FD);
        const v2f* b = (const v2f*)(Wff + lane * FD);
#pragma unroll
        for (int j = 0; j < 16; ++j) { wA2[j] = a[j]; wB2[j] = b[j]; }
        const v2f* c = (const v2f*)(Wfs + lane * SD);
#pragma unroll
        for (int k = 0; k < 8; ++k) wC2[k] = c[k];
        bA = bgh[lane]; bB = bff[lane];
    } else if (lane < FD + SD) {
        int s = lane - FD;
        const v2f* a = (const v2f*)(Wsgf + s * FD);
#pragma unroll
        for (int j = 0; j < 16; ++j) { wA2[j] = a[j]; wB2[j] = (v2f){0.f, 0.f}; }
        const v2f* c = (const v2f*)(Wsgs + s * SD);
#pragma unroll
        for (int k = 0; k < 8; ++k) wC2[k] = c[k];
        bA = bsgf[s];
    } else {
        int s = lane - 48;
        const v2f* a = (const v2f*)(Wsf + s * FD);
#pragma unroll
        for (int j = 0; j < 16; ++j) { wA2[j] = a[j]; wB2[j] = (v2f){0.f, 0.f}; }
        const v2f* c = (const v2f*)(Wss + s * SD);
#pragma unroll
        for (int k = 0; k < 8; ++k) wC2[k] = c[k];
        bA = bss[s];
    }

    float hf = 0.f, hs = 0.f, pA = 0.f;

    const int li = lane & 31;
    const float* gp = xt + (size_t)li * NSP;
    const float* pp = gp + 32 * NSP;
    const float* fp = gp + 64 * NSP;
    v4f g4 = *(const v4f*)gp;
    v4f p4 = *(const v4f*)pp;
    v4f f4 = *(const v4f*)fp;

    float* sp = states + lane;
    const bool isSlowState = (lane >= FD) && (lane < FD + SD);
    const bool isFast = (lane < FD);
    const bool isST = (lane >= 48);
    const float tsc = isST ? -2.f : -1.f;

    for (int t4 = 0; t4 < NSTEP; t4 += 4) {
        // prefetch next 4 steps (slack covers tail; poison values never consumed)
        v4f ng = *(const v4f*)(gp + t4 + 4);
        v4f np = *(const v4f*)(pp + t4 + 4);
        v4f nf = *(const v4f*)(fp + t4 + 4);

#pragma unroll
        for (int d = 0; d < 4; ++d) {
            float gx = g4[d], px = p4[d], fx = f4[d];

            // ---- L1: pC = sum_k wC[k] * hs[k]  (hs in lanes 32..47) ----
            float pC;
            {
                v2f sv[8];
#pragma unroll
                for (int k = 0; k < 8; ++k)
                    sv[k] = (v2f){rl(hs, FD + 2 * k), rl(hs, FD + 2 * k + 1)};
                v2f a0 = {0.f,0.f}, a1 = {0.f,0.f}, a2 = {0.f,0.f}, a3 = {0.f,0.f};
                a0 += wC2[0] * sv[0]; a1 += wC2[1] * sv[1];
                a2 += wC2[2] * sv[2]; a3 += wC2[3] * sv[3];
                a0 += wC2[4] * sv[4]; a1 += wC2[5] * sv[5];
                a2 += wC2[6] * sv[6]; a3 += wC2[7] * sv[7];
                v2f r = (a0 + a1) + (a2 + a3);
                pC = r.x + r.y;
            }

            // gate (fast lanes): pA = W_gate_h @ hf carried from previous L2
            float ga   = pA + bA + gx;
            float ge   = __expf(-ga);
            float gate = __builtin_amdgcn_rcpf(1.f + ge);
            float hA   = hf + gate * px;

            float c1 = bB + fx + pC;

            // ---- relax 1 ----
            float hB;
            {
                v2f sv[16];
#pragma unroll
                for (int j = 0; j < 16; ++j)
                    sv[j] = (v2f){rl(hA, 2 * j), rl(hA, 2 * j + 1)};
                v2f a0 = {0.f,0.f}, a1 = {0.f,0.f}, a2 = {0.f,0.f}, a3 = {0.f,0.f};
#pragma unroll
                for (int j = 0; j < 16; j += 4) {
                    a0 += wB2[j]     * sv[j];
                    a1 += wB2[j + 1] * sv[j + 1];
                    a2 += wB2[j + 2] * sv[j + 2];
                    a3 += wB2[j + 3] * sv[j + 3];
                }
                v2f r = (a0 + a1) + (a2 + a3);
                float acc = c1 + r.x + r.y;
                float e  = __expf(-2.f * acc);
                float tg = 2.f * __builtin_amdgcn_rcpf(1.f + e) - 1.f;
                hB = hA + 0.25f * (tg - hA);
            }
            // ---- relax 2 ----
            {
                v2f sv[16];
#pragma unroll
                for (int j = 0; j < 16; ++j)
                    sv[j] = (v2f){rl(hB, 2 * j), rl(hB, 2 * j + 1)};
                v2f a0 = {0.f,0.f}, a1 = {0.f,0.f}, a2 = {0.f,0.f}, a3 = {0.f,0.f};
#pragma unroll
                for (int j = 0; j < 16; j += 4) {
                    a0 += wB2[j]     * sv[j];
                    a1 += wB2[j + 1] * sv[j + 1];
                    a2 += wB2[j + 2] * sv[j + 2];
                    a3 += wB2[j + 3] * sv[j + 3];
                }
                v2f r = (a0 + a1) + (a2 + a3);
                float acc = c1 + r.x + r.y;
                float e  = __expf(-2.f * acc);
                float tg = 2.f * __builtin_amdgcn_rcpf(1.f + e) - 1.f;
                hf = hB + 0.25f * (tg - hB);
            }

            // ---- L2: pA = sum_j wA[j] * hf_new[j] ----
            {
                v2f sv[16];
#pragma unroll
                for (int j = 0; j < 16; ++j)
                    sv[j] = (v2f){rl(hf, 2 * j), rl(hf, 2 * j + 1)};
                v2f a0 = {0.f,0.f}, a1 = {0.f,0.f}, a2 = {0.f,0.f}, a3 = {0.f,0.f};
#pragma unroll
                for (int j = 0; j < 16; j += 4) {
                    a0 += wA2[j]     * sv[j];
                    a1 += wA2[j + 1] * sv[j + 1];
                    a2 += wA2[j + 2] * sv[j + 2];
                    a3 += wA2[j + 3] * sv[j + 3];
                }
                v2f r = (a0 + a1) + (a2 + a3);
                pA = r.x + r.y;
            }

            // ---- slow update: lanes 32-47 sigmoid, lanes 48-63 tanh ----
            {
                float u = bA + pC + pA;
                float e = __expf(tsc * u);
                float r = __builtin_amdgcn_rcpf(1.f + e);
                float v = isST ? (2.f * r - 1.f) : r;
                float stv = __shfl(v, lane + 16, 64);
                float hsn = hs + 0.02f * v * (stv - hs);
                hs = isSlowState ? hsn : hs;
            }

            // branchless state store (stride-64 rows)
            sp[0] = isFast ? hf : hs;
            sp += SROW;
        }
        g4 = ng; p4 = np; f4 = nf;
    }
}

// ---------------- K3: vocab logits, LDS-staged tiles + max-free expsum ----------------
// |logit| < 0.5 (xavier gain 0.5, bounded state) -> plain exp-sum safe in fp32.
// 128-row tiles of Wout staged cooperatively (coalesced float4), then all
// threads broadcast-read from LDS (same-address = conflict-free) -> removes
// the per-thread L2/L3 latency chain that dominated the old version.
__global__ __launch_bounds__(256, 2) void logits_kernel(
    const float* __restrict__ Wout, const float* __restrict__ bout,
    const float* __restrict__ states, float* __restrict__ pm)
{
    __shared__ __align__(16) float wtile[TR * CD];
    __shared__ float btile[TR];

    int tb = blockIdx.y * 512 + threadIdx.x;     // t0 = tb, t1 = tb + 256
    int chunk = blockIdx.x;
    int r0 = chunk * ROWS_PER;
    int r1 = min(r0 + ROWS_PER, VOCAB);

    v2f s0[24], s1[24];
    {
        const v2f* q0 = (const v2f*)(states + (size_t)tb * SROW);
        const v2f* q1 = (const v2f*)(states + (size_t)(tb + 256) * SROW);
#pragma unroll
        for (int k = 0; k < 24; ++k) { s0[k] = q0[k]; s1[k] = q1[k]; }
    }

    float sx = 0.f, sy = 0.f;
    for (int rt = r0; rt < r1; rt += TR) {
        int nrows = min(TR, r1 - rt);
        int nflt  = nrows * CD;                  // always multiple of 4
        __syncthreads();                         // protect previous tile reads
        const float* src = Wout + (size_t)rt * CD;
        for (int idx = threadIdx.x * 4; idx < nflt; idx += 1024)
            *(v4f*)(wtile + idx) = *(const v4f*)(src + idx);
        for (int idx = threadIdx.x; idx < nrows; idx += 256)
            btile[idx] = bout[rt + idx];
        __syncthreads();

        for (int r = 0; r < nrows; ++r) {
            const v2f* w = (const v2f*)(wtile + r * CD);
            v2f a0 = {0.f,0.f}, b0 = {0.f,0.f}, a1 = {0.f,0.f}, b1 = {0.f,0.f};
#pragma unroll
            for (int k = 0; k < 24; k += 2) {
                v2f wk0 = w[k], wk1 = w[k + 1];
                a0 += wk0 * s0[k];
                a1 += wk0 * s1[k];
                b0 += wk1 * s0[k + 1];
                b1 += wk1 * s1[k + 1];
            }
            v2f v0 = a0 + b0, v1 = a1 + b1;
            float bo = btile[r];
            sx += __expf(v0.x + v0.y + bo);
            sy += __expf(v1.x + v1.y + bo);
        }
    }
    pm[(size_t)tb * VC + chunk]         = sx;
    pm[(size_t)(tb + 256) * VC + chunk] = sy;
}

// ---------------- K4: target logit + per-timestep NLL (merged) ----------------
__global__ __launch_bounds__(256) void nll_kernel(
    const int* __restrict__ tok, const float* __restrict__ Wout,
    const float* __restrict__ bout, const float* __restrict__ states,
    const float* __restrict__ pm, float* __restrict__ nll)
{
    int t = blockIdx.x * 256 + threadIdx.x;
    if (t >= NSTEP) return;
    int tgt = tok[t + 1];
    const float* w = Wout + (size_t)tgt * CD;
    float acc = bout[tgt];
#pragma unroll
    for (int k = 0; k < CD; ++k) acc += w[k] * states[(size_t)t * SROW + k];
    const float* p = pm + (size_t)t * VC;
    float ssum = 0.f;
#pragma unroll
    for (int c = 0; c < VC; ++c) ssum += p[c];
    nll[t] = __logf(ssum) - acc;
}

// ---------------- K5: mean reduce ----------------
__global__ __launch_bounds__(256) void reduce_kernel(
    const float* __restrict__ nll, float* __restrict__ out)
{
    __shared__ float red[256];
    float local = 0.f;
    for (int t = threadIdx.x; t < NSTEP; t += 256) local += nll[t];
    red[threadIdx.x] = local;
    __syncthreads();
    for (int off = 128; off > 0; off >>= 1) {
        if (threadIdx.x < off) red[threadIdx.x] += red[threadIdx.x + off];
        __syncthreads();
    }
    if (threadIdx.x == 0) out[0] = red[0] / (float)NSTEP;
}

extern "C" void kernel_launch(void* const* d_in, const int* in_sizes, int n_in,
                              void* d_out, int out_size, void* d_ws, size_t ws_size,
                              hipStream_t stream) {
    const int*   tok   = (const int*)  d_in[0];
    const float* embed = (const float*)d_in[1];
    const float* Wgh   = (const float*)d_in[2];
    const float* bgh   = (const float*)d_in[3];
    const float* Wgx   = (const float*)d_in[4];
    const float* Wxp   = (const float*)d_in[5];
    const float* Wff   = (const float*)d_in[6];
    const float* bff   = (const float*)d_in[7];
    const float* Wfs   = (const float*)d_in[8];
    const float* Wxf   = (const float*)d_in[9];
    const float* Wsgf  = (const float*)d_in[10];
    const float* bsgf  = (const float*)d_in[11];
    const float* Wsgs  = (const float*)d_in[12];
    const float* Wss   = (const float*)d_in[13];
    const float* bss   = (const float*)d_in[14];
    const float* Wsf   = (const float*)d_in[15];
    const float* Wout  = (const float*)d_in[16];
    const float* bout  = (const float*)d_in[17];

    float* ws     = (float*)d_ws;
    float* xt     = ws + WS_XT;
    float* states = ws + WS_STATES;
    float* pm     = ws + WS_PM;
    float* nll    = ws + WS_NLL;
    float* outf   = (float*)d_out;

    xterm_kernel<<<dim3(NSTEP / 8), dim3(256), 0, stream>>>(tok, embed, Wgx, Wxp, Wxf, xt);
    scan_kernel<<<dim3(1), dim3(64), 0, stream>>>(Wgh, bgh, Wff, bff, Wfs, Wsgf, bsgf,
                                                  Wsgs, Wss, bss, Wsf, xt, states);
    logits_kernel<<<dim3(VC, NSTEP / 512), dim3(256), 0, stream>>>(Wout, bout, states, pm);
    nll_kernel<<<dim3(NSTEP / 256), dim3(256), 0, stream>>>(tok, Wout, bout, states, pm, nll);
    reduce_kernel<<<dim3(1), dim3(256), 0, stream>>>(nll, outf);
}